// Round 8
// baseline (1148.173 us; speedup 1.0000x reference)
//
#include <hip/hip_runtime.h>
#include <hip/hip_fp16.h>
#include <stdint.h>

#define HDIM 2048
#define BATCH 16
#define TLEN 512
#define TH   1048576        // TLEN*HDIM
#define OUT_MAIN 16777216   // BATCH*TLEN*HDIM

using floatx4 = __attribute__((ext_vector_type(4))) float;
using shortx8 = __attribute__((ext_vector_type(8))) short;
using halfx8  = __attribute__((ext_vector_type(8))) _Float16;
typedef unsigned long long ull;

static __device__ __forceinline__ unsigned f16bits(float f) {
    _Float16 h = (_Float16)f;
    return (unsigned)*(unsigned short*)&h;
}

// ---------------- cast kernels ----------------
__global__ void cast_x_kernel(const float* __restrict__ x, _Float16* __restrict__ xh, int n) {
    int i = blockIdx.x * blockDim.x + threadIdx.x;
    int stride = gridDim.x * blockDim.x;
    for (; i < n; i += stride) xh[i] = (_Float16)x[i];
}

__global__ void cast_w_kernel(const float* __restrict__ W,
                              _Float16* __restrict__ wxh,
                              _Float16* __restrict__ whh) {
    int i = blockIdx.x * blockDim.x + threadIdx.x;
    int stride = gridDim.x * blockDim.x;
    for (; i < HDIM * HDIM; i += stride) {
        int g = i >> 11, k = i & (HDIM - 1);
        wxh[i] = (_Float16)W[g * (2 * HDIM) + k];
        whh[i] = (_Float16)W[g * (2 * HDIM) + HDIM + k];
    }
}

// Transpose Wh -> whT (fp16). Runs after gemm_u; output aliases dead xh.
__global__ void transpose_wh_kernel(const float* __restrict__ W,
                                    _Float16* __restrict__ whT) {
    __shared__ float tile[32][33];
    int bx = blockIdx.x * 32, by = blockIdx.y * 32;
    int tx = threadIdx.x, ty = threadIdx.y;  // (32,8)
#pragma unroll
    for (int r = 0; r < 32; r += 8)
        tile[ty + r][tx] = W[(size_t)(by + ty + r) * (2 * HDIM) + HDIM + bx + tx];
    __syncthreads();
#pragma unroll
    for (int r = 0; r < 32; r += 8)
        whT[(size_t)(bx + ty + r) * HDIM + by + tx] = (_Float16)tile[tx][ty + r];
}

// ---------------- phase A: u = x @ Wx^T + b -> out (fp32) + uh (fp16) ----------------
__global__ __launch_bounds__(256) void gemm_u_kernel(
    const _Float16* __restrict__ xh,
    const _Float16* __restrict__ wxh,
    const float* __restrict__ bias,
    float* __restrict__ out,
    _Float16* __restrict__ uh)
{
    __shared__ __align__(16) short As[4 * 128 * 8];
    __shared__ __align__(16) short Bs[4 * 128 * 8];

    const int j = threadIdx.x;
    const int m0 = blockIdx.x * 128;
    const int n0 = blockIdx.y * 128;
    const int w = j >> 6, lane = j & 63;
    const int wm = (w >> 1) * 64, wn = (w & 1) * 64;
    const int quad = lane >> 4, l15 = lane & 15;

    const int mA0 = j & 127, kg0 = j >> 7;
    const int mA1 = (j + 256) & 127, kg1 = (j + 256) >> 7;

    floatx4 acc[4][4] = {};

    shortx8 ra0 = *(const shortx8*)(xh  + (size_t)(m0 + mA0) * HDIM + kg0 * 8);
    shortx8 ra1 = *(const shortx8*)(xh  + (size_t)(m0 + mA1) * HDIM + kg1 * 8);
    shortx8 rb0 = *(const shortx8*)(wxh + (size_t)(n0 + mA0) * HDIM + kg0 * 8);
    shortx8 rb1 = *(const shortx8*)(wxh + (size_t)(n0 + mA1) * HDIM + kg1 * 8);

    for (int kt = 0; kt < 64; ++kt) {
        ((shortx8*)As)[kg0 * 128 + mA0] = ra0;
        ((shortx8*)As)[kg1 * 128 + mA1] = ra1;
        ((shortx8*)Bs)[kg0 * 128 + mA0] = rb0;
        ((shortx8*)Bs)[kg1 * 128 + mA1] = rb1;
        __syncthreads();

        if (kt < 63) {
            int k = (kt + 1) * 32;
            ra0 = *(const shortx8*)(xh  + (size_t)(m0 + mA0) * HDIM + k + kg0 * 8);
            ra1 = *(const shortx8*)(xh  + (size_t)(m0 + mA1) * HDIM + k + kg1 * 8);
            rb0 = *(const shortx8*)(wxh + (size_t)(n0 + mA0) * HDIM + k + kg0 * 8);
            rb1 = *(const shortx8*)(wxh + (size_t)(n0 + mA1) * HDIM + k + kg1 * 8);
        }

        halfx8 af[4], bf[4];
#pragma unroll
        for (int mt = 0; mt < 4; ++mt)
            af[mt] = ((const halfx8*)As)[quad * 128 + wm + mt * 16 + l15];
#pragma unroll
        for (int nt = 0; nt < 4; ++nt)
            bf[nt] = ((const halfx8*)Bs)[quad * 128 + wn + nt * 16 + l15];
#pragma unroll
        for (int mt = 0; mt < 4; ++mt)
#pragma unroll
            for (int nt = 0; nt < 4; ++nt)
                acc[mt][nt] = __builtin_amdgcn_mfma_f32_16x16x32_f16(af[mt], bf[nt], acc[mt][nt], 0, 0, 0);
        __syncthreads();
    }

#pragma unroll
    for (int nt = 0; nt < 4; ++nt) {
        int gn = n0 + wn + nt * 16 + l15;
        float bv = bias[gn];
#pragma unroll
        for (int mt = 0; mt < 4; ++mt) {
#pragma unroll
            for (int r = 0; r < 4; ++r) {
                int gm = m0 + wm + mt * 16 + quad * 4 + r;
                float v = acc[mt][nt][r] + bv;
                out[(size_t)gm * HDIM + gn] = v;
                uh[(size_t)gm * HDIM + gn] = (_Float16)v;
            }
        }
    }
}

// ---------------- Wh2 = Wh*Wh (fp16 single-plane) ----------------
__global__ __launch_bounds__(256) void gemm_w2_kernel(
    const _Float16* __restrict__ whh,
    const _Float16* __restrict__ wT,
    _Float16* __restrict__ w2)
{
    __shared__ __align__(16) short As[4 * 128 * 8];
    __shared__ __align__(16) short Bs[4 * 128 * 8];

    const int j = threadIdx.x;
    const int m0 = blockIdx.x * 128;
    const int n0 = blockIdx.y * 128;
    const int w = j >> 6, lane = j & 63;
    const int wm = (w >> 1) * 64, wn = (w & 1) * 64;
    const int quad = lane >> 4, l15 = lane & 15;

    const int mA0 = j & 127, kg0 = j >> 7;
    const int mA1 = (j + 256) & 127, kg1 = (j + 256) >> 7;

    floatx4 acc[4][4] = {};

    shortx8 ra0 = *(const shortx8*)(whh + (size_t)(m0 + mA0) * HDIM + kg0 * 8);
    shortx8 ra1 = *(const shortx8*)(whh + (size_t)(m0 + mA1) * HDIM + kg1 * 8);
    shortx8 rb0 = *(const shortx8*)(wT  + (size_t)(n0 + mA0) * HDIM + kg0 * 8);
    shortx8 rb1 = *(const shortx8*)(wT  + (size_t)(n0 + mA1) * HDIM + kg1 * 8);

    for (int kt = 0; kt < 64; ++kt) {
        ((shortx8*)As)[kg0 * 128 + mA0] = ra0;
        ((shortx8*)As)[kg1 * 128 + mA1] = ra1;
        ((shortx8*)Bs)[kg0 * 128 + mA0] = rb0;
        ((shortx8*)Bs)[kg1 * 128 + mA1] = rb1;
        __syncthreads();

        if (kt < 63) {
            int k = (kt + 1) * 32;
            ra0 = *(const shortx8*)(whh + (size_t)(m0 + mA0) * HDIM + k + kg0 * 8);
            ra1 = *(const shortx8*)(whh + (size_t)(m0 + mA1) * HDIM + k + kg1 * 8);
            rb0 = *(const shortx8*)(wT  + (size_t)(n0 + mA0) * HDIM + k + kg0 * 8);
            rb1 = *(const shortx8*)(wT  + (size_t)(n0 + mA1) * HDIM + k + kg1 * 8);
        }

        halfx8 af[4], bf[4];
#pragma unroll
        for (int mt = 0; mt < 4; ++mt)
            af[mt] = ((const halfx8*)As)[quad * 128 + wm + mt * 16 + l15];
#pragma unroll
        for (int nt = 0; nt < 4; ++nt)
            bf[nt] = ((const halfx8*)Bs)[quad * 128 + wn + nt * 16 + l15];
#pragma unroll
        for (int mt = 0; mt < 4; ++mt)
#pragma unroll
            for (int nt = 0; nt < 4; ++nt)
                acc[mt][nt] = __builtin_amdgcn_mfma_f32_16x16x32_f16(af[mt], bf[nt], acc[mt][nt], 0, 0, 0);
        __syncthreads();
    }

#pragma unroll
    for (int nt = 0; nt < 4; ++nt) {
        int gn = n0 + wn + nt * 16 + l15;
#pragma unroll
        for (int mt = 0; mt < 4; ++mt)
#pragma unroll
            for (int r = 0; r < 4; ++r) {
                int gm = m0 + wm + mt * 16 + quad * 4 + r;
                w2[(size_t)gm * HDIM + gn] = (_Float16)acc[mt][nt][r];
            }
    }
}

// ---------------- v = u + Wh*u_shift (fp16; t==0 rows keep u) ----------------
__global__ __launch_bounds__(256) void gemm_v_kernel(
    const _Float16* __restrict__ uh,
    const _Float16* __restrict__ whh,
    float* __restrict__ out)
{
    __shared__ __align__(16) short As[4 * 128 * 8];
    __shared__ __align__(16) short Bs[4 * 128 * 8];

    const int j = threadIdx.x;
    const int m0 = blockIdx.x * 128;
    const int n0 = blockIdx.y * 128;
    const int w = j >> 6, lane = j & 63;
    const int wm = (w >> 1) * 64, wn = (w & 1) * 64;
    const int quad = lane >> 4, l15 = lane & 15;

    const int mA0 = j & 127, kg0 = j >> 7;
    const int mA1 = (j + 256) & 127, kg1 = (j + 256) >> 7;

    int rowA0 = m0 + mA0 - 1; if (rowA0 < 0) rowA0 = 0;
    int rowA1 = m0 + mA1 - 1; if (rowA1 < 0) rowA1 = 0;

    floatx4 acc[4][4] = {};

    shortx8 ra0 = *(const shortx8*)(uh  + (size_t)rowA0 * HDIM + kg0 * 8);
    shortx8 ra1 = *(const shortx8*)(uh  + (size_t)rowA1 * HDIM + kg1 * 8);
    shortx8 rb0 = *(const shortx8*)(whh + (size_t)(n0 + mA0) * HDIM + kg0 * 8);
    shortx8 rb1 = *(const shortx8*)(whh + (size_t)(n0 + mA1) * HDIM + kg1 * 8);

    for (int kt = 0; kt < 64; ++kt) {
        ((shortx8*)As)[kg0 * 128 + mA0] = ra0;
        ((shortx8*)As)[kg1 * 128 + mA1] = ra1;
        ((shortx8*)Bs)[kg0 * 128 + mA0] = rb0;
        ((shortx8*)Bs)[kg1 * 128 + mA1] = rb1;
        __syncthreads();

        if (kt < 63) {
            int k = (kt + 1) * 32;
            ra0 = *(const shortx8*)(uh  + (size_t)rowA0 * HDIM + k + kg0 * 8);
            ra1 = *(const shortx8*)(uh  + (size_t)rowA1 * HDIM + k + kg1 * 8);
            rb0 = *(const shortx8*)(whh + (size_t)(n0 + mA0) * HDIM + k + kg0 * 8);
            rb1 = *(const shortx8*)(whh + (size_t)(n0 + mA1) * HDIM + k + kg1 * 8);
        }

        halfx8 af[4], bf[4];
#pragma unroll
        for (int mt = 0; mt < 4; ++mt)
            af[mt] = ((const halfx8*)As)[quad * 128 + wm + mt * 16 + l15];
#pragma unroll
        for (int nt = 0; nt < 4; ++nt)
            bf[nt] = ((const halfx8*)Bs)[quad * 128 + wn + nt * 16 + l15];
#pragma unroll
        for (int mt = 0; mt < 4; ++mt)
#pragma unroll
            for (int nt = 0; nt < 4; ++nt)
                acc[mt][nt] = __builtin_amdgcn_mfma_f32_16x16x32_f16(af[mt], bf[nt], acc[mt][nt], 0, 0, 0);
        __syncthreads();
    }

#pragma unroll
    for (int nt = 0; nt < 4; ++nt) {
        int gn = n0 + wn + nt * 16 + l15;
#pragma unroll
        for (int mt = 0; mt < 4; ++mt)
#pragma unroll
            for (int r = 0; r < 4; ++r) {
                int gm = m0 + wm + mt * 16 + quad * 4 + r;
                float uval = out[(size_t)gm * HDIM + gn];
                float res = ((gm & 511) == 0) ? uval : (acc[mt][nt][r] + uval);
                out[(size_t)gm * HDIM + gn] = res;
            }
    }
}

// ---------------- phase B: two parity chains, fp16 ring, 64 WGs x 1024 thr ----------------
// o_t = v_t + Wh2 * o_{t-2}. Scan is L3 BROADCAST-TRAFFIC bound (r2: 2x
// transactions -> 2x time; r6: 1/2 bytes -> 0.6x time). Traffic = WGs/chain x
// 64KB x steps, since every WG reads the FULL h vector. This round halves the
// amplification: 32 WGs/chain (was 64), 1024 threads each, 64 output cols/WG
// (4 gt tiles), 16 waves each owning a 128-wide K-slice. Per-wave inner loop
// unchanged (16 MFMA, 4x16B ring loads); reduce now over 16 waves (ps 69.6KB).
// Flag protocol and write-once 512-slot ring unchanged (proven correct).
__global__ __launch_bounds__(1024) void rnn_scan_kernel(
    const _Float16* __restrict__ w2,
    short* __restrict__ ring,                // [512][32768] shorts (fp16 bits)
    float* __restrict__ out,
    unsigned* __restrict__ flags)            // [2][32][32] uint, 128B stride
{
    __shared__ float ps[16 * 4 * 16 * 17];   // [wave][gt][drow][17]

    const int j = threadIdx.x;
    const int w = j >> 6, lane = j & 63;     // w: 0..15 (K-slice owner)
    const int quad = lane >> 4, l15 = lane & 15;
    const int chain = blockIdx.x & 1;
    const int rank = blockIdx.x >> 1;        // 0..31
    const int n0 = rank * 64;

    unsigned* myflag = flags + (chain * 32 + rank) * 32;
    const unsigned* pollbase = flags + chain * 32 * 32;

    // Wh2 slice: 64 cols (4 gt tiles), K-slice w*128..+128 (4 c-groups of 32)
    halfx8 af[4][4];
#pragma unroll
    for (int gt = 0; gt < 4; ++gt)
#pragma unroll
        for (int c = 0; c < 4; ++c) {
            int row = n0 + gt * 16 + l15;
            int k = w * 128 + c * 32 + quad * 8;
            af[gt][c] = *(const halfx8*)(w2 + (size_t)row * HDIM + k);
        }

    const int rn = j & 63, rb = j >> 6;      // rn: col 0..63, rb: batch 0..15
    const int gt_r = rn >> 4, row_r = rn & 15;

    for (int s = 0; s < 256; ++s) {
        const int t = chain + 2 * s;
        short* slot_next = ring + (size_t)(s * 2 + chain) * 32768;

        // prefetch v (overlaps poll latency)
        float uv = out[(size_t)rb * TH + (size_t)t * HDIM + n0 + rn];

        floatx4 acc[4][2] = {};
        if (s > 0) {
            const short* slot_prev = ring + (size_t)((s - 1) * 2 + chain) * 32768;
            // wave-local wait: this wave's 128-wide K-slice = 2 producer ranks
            if (lane < 2) {
                const unsigned* fp = pollbase + (w * 2 + lane) * 32;
                while (__hip_atomic_load(fp, __ATOMIC_RELAXED, __HIP_MEMORY_SCOPE_AGENT) < (unsigned)s) {}
            }
            __asm__ __volatile__("" ::: "memory");

#pragma unroll
            for (int c = 0; c < 4; ++c) {
                int kg = w * 16 + c * 4 + quad;
                halfx8 bh = *(const halfx8*)(slot_prev + kg * 128 + l15 * 8);
                int cp = c & 1;
                acc[0][cp] = __builtin_amdgcn_mfma_f32_16x16x32_f16(af[0][c], bh, acc[0][cp], 0, 0, 0);
                acc[1][cp] = __builtin_amdgcn_mfma_f32_16x16x32_f16(af[1][c], bh, acc[1][cp], 0, 0, 0);
                acc[2][cp] = __builtin_amdgcn_mfma_f32_16x16x32_f16(af[2][c], bh, acc[2][cp], 0, 0, 0);
                acc[3][cp] = __builtin_amdgcn_mfma_f32_16x16x32_f16(af[3][c], bh, acc[3][cp], 0, 0, 0);
            }
        }

#pragma unroll
        for (int gt = 0; gt < 4; ++gt) {
            floatx4 a = acc[gt][0] + acc[gt][1];
#pragma unroll
            for (int r = 0; r < 4; ++r)
                ps[((w * 4 + gt) * 16 + quad * 4 + r) * 17 + l15] = a[r];
        }
        __syncthreads();

        float sv_f = uv;
#pragma unroll
        for (int ww = 0; ww < 16; ++ww)
            sv_f += ps[((ww * 4 + gt_r) * 16 + row_r) * 17 + rb];

        int n = n0 + rn;

        // fp16 producer-side cast, pack (n, n+1) into one 4B relaxed agent store
        unsigned hb = f16bits(sv_f);
        unsigned hb2 = __shfl_down(hb, 1);
        if ((j & 1) == 0) {
            int idx = (n >> 3) * 128 + rb * 8 + (n & 7);  // n even -> 4B aligned
            __hip_atomic_store((unsigned*)(slot_next + idx), hb | (hb2 << 16),
                               __ATOMIC_RELAXED, __HIP_MEMORY_SCOPE_AGENT);
        }

        // barrier drains ring stores (vmcnt(0) before s_barrier), then publish
        __syncthreads();
        if (j == 0)
            __hip_atomic_store(myflag, (unsigned)(s + 1), __ATOMIC_RELAXED, __HIP_MEMORY_SCOPE_AGENT);

        // out stores AFTER the flag: off the inter-WG critical path
        out[(size_t)rb * TH + (size_t)t * HDIM + n] = sv_f;
        if (t == TLEN - 1) out[(size_t)OUT_MAIN + (size_t)rb * HDIM + n] = sv_f;
    }
}

// ---------------- launcher ----------------
extern "C" void kernel_launch(void* const* d_in, const int* in_sizes, int n_in,
                              void* d_out, int out_size, void* d_ws, size_t ws_size,
                              hipStream_t stream) {
    (void)in_sizes; (void)n_in; (void)out_size; (void)ws_size;
    const float* x    = (const float*)d_in[0];
    const float* W    = (const float*)d_in[1];
    const float* bias = (const float*)d_in[2];
    float* out = (float*)d_out;
    char* ws = (char*)d_ws;

    // Memory plan (80.0 MB + 16KB flags; fp16 single-plane everywhere):
    //  xh   [0,32M)   fp16 x          (dead after gemm_u)
    //  whT  [0,8M)    fp16 Wh^T       (transpose after gemm_u; dead after gemm_w2)
    //  w2   [8,16M)   fp16 Wh^2       (gemm_w2 -> scan)
    //  ring [16,48M)  512 slots x 64KB (scan only; aliases dead xh tail/wxh/whh)
    //  wxh  [32,40M)  fp16 Wx         (dead after gemm_u)
    //  whh  [40,48M)  fp16 Wh         (dead after gemm_w2)
    //  uh   [48,80M)  fp16 u          (dead after gemm_v)
    //  flags [80M,+16K)
    _Float16* xh  = (_Float16*)(ws);
    _Float16* whT = (_Float16*)(ws);
    _Float16* w2  = (_Float16*)(ws + 8388608);
    short*    ring = (short*)(ws + 16777216);
    _Float16* wxh = (_Float16*)(ws + 33554432);
    _Float16* whh = (_Float16*)(ws + 41943040);
    _Float16* uh  = (_Float16*)(ws + 50331648);
    unsigned* flags = (unsigned*)(ws + 83886080);

    hipMemsetAsync(ws + 83886080, 0, 16384, stream);

    cast_x_kernel<<<8192, 256, 0, stream>>>(x, xh, OUT_MAIN);
    cast_w_kernel<<<8192, 256, 0, stream>>>(W, wxh, whh);
    gemm_u_kernel<<<dim3(64, 16), 256, 0, stream>>>(xh, wxh, bias, out, uh);
    transpose_wh_kernel<<<dim3(64, 64), dim3(32, 8), 0, stream>>>(W, whT);
    gemm_v_kernel<<<dim3(64, 16), 256, 0, stream>>>(uh, whh, out);
    gemm_w2_kernel<<<dim3(16, 16), 256, 0, stream>>>(whh, whT, w2);
    rnn_scan_kernel<<<64, 1024, 0, stream>>>(w2, ring, out, flags);
}